// Round 1
// baseline (103.601 us; speedup 1.0000x reference)
//
#include <hip/hip_runtime.h>

// GNN edge head: pred[e,0] = dot(nf[src[e]], nf[dst[e]])
//                pred[e,1+k] = dot(nf[src[e]], nf[neg[e,k]]),  k in [0,8)
// Output: d_out = [ pred flat (E*9 f32) | edge_label as f32 (E) ]
//
// One 16-lane group per edge. Lane sub loads float4 at row element sub*4
// (256 B fully-coalesced segment per row gather). u kept in registers and
// reused across the 9 dots; 4-step shfl_xor reduce per dot.

__global__ __launch_bounds__(256) void gnn_edge_head_kernel(
    const float* __restrict__ nf,     // [N, 64]
    const int*   __restrict__ src,    // [E]  (edge_label_index[0])
    const int*   __restrict__ dst,    // [E]  (edge_label_index[1])
    const int*   __restrict__ neg,    // [E, 8]
    const int*   __restrict__ label,  // [E]
    float*       __restrict__ out,    // [E*9 + E]
    int E)
{
    const int sub = threadIdx.x & 15;                 // lane within 16-lane group
    const int grp = threadIdx.x >> 4;                 // group within block
    const int groupsPerBlock = blockDim.x >> 4;
    const int stride = gridDim.x * groupsPerBlock;

    for (int e = blockIdx.x * groupsPerBlock + grp; e < E; e += stride) {
        const int us = src[e];
        const int vs = dst[e];

        const float4 u4 = reinterpret_cast<const float4*>(nf + (size_t)us * 64)[sub];

        // positive
        {
            const float4 v4 = reinterpret_cast<const float4*>(nf + (size_t)vs * 64)[sub];
            float s = u4.x * v4.x + u4.y * v4.y + u4.z * v4.z + u4.w * v4.w;
            s += __shfl_xor(s, 1);
            s += __shfl_xor(s, 2);
            s += __shfl_xor(s, 4);
            s += __shfl_xor(s, 8);
            if (sub == 0) out[(size_t)e * 9] = s;
        }

        // negatives
        #pragma unroll
        for (int k = 0; k < 8; ++k) {
            const int ni = neg[(size_t)e * 8 + k];
            const float4 n4 = reinterpret_cast<const float4*>(nf + (size_t)ni * 64)[sub];
            float t = u4.x * n4.x + u4.y * n4.y + u4.z * n4.z + u4.w * n4.w;
            t += __shfl_xor(t, 1);
            t += __shfl_xor(t, 2);
            t += __shfl_xor(t, 4);
            t += __shfl_xor(t, 8);
            if (sub == 0) out[(size_t)e * 9 + 1 + k] = t;
        }

        // second output: edge_label cast to float
        if (sub == 1) out[(size_t)E * 9 + e] = (float)label[e];
    }
}

extern "C" void kernel_launch(void* const* d_in, const int* in_sizes, int n_in,
                              void* d_out, int out_size, void* d_ws, size_t ws_size,
                              hipStream_t stream)
{
    const float* nf    = (const float*)d_in[0];   // [N*64] f32
    const int*   eli   = (const int*)d_in[1];     // [2*E]
    const int*   neg   = (const int*)d_in[2];     // [E*8]
    const int*   label = (const int*)d_in[3];     // [E]
    float*       out   = (float*)d_out;

    const int E = in_sizes[3];                    // 262144
    const int* src = eli;
    const int* dst = eli + E;

    const int block = 256;
    const int groupsPerBlock = block / 16;        // 16 edges per block
    const int grid = (E + groupsPerBlock - 1) / groupsPerBlock;  // 16384

    gnn_edge_head_kernel<<<grid, block, 0, stream>>>(nf, src, dst, neg, label, out, E);
}

// Round 2
// 99.558 us; speedup vs baseline: 1.0406x; 1.0406x over previous
//
#include <hip/hip_runtime.h>

// GNN edge head: pred[e,0] = dot(nf[src[e]], nf[dst[e]])
//                pred[e,1+k] = dot(nf[src[e]], nf[neg[e,k]]),  k in [0,8)
// Output: d_out = [ pred flat (E*9 f32) | edge_label as f32 (E) ]
//
// One 16-lane group per edge. Lane sub loads float4 at row element sub*4.
// ALL 10 row gathers issued before any reduce (max loads in flight per wave);
// neg indices loaded as 2x int4; butterflies deferred; single coalesced
// select-chain store by lanes 0..8.

__device__ __forceinline__ float dot4(float4 a, float4 b) {
    return fmaf(a.x, b.x, fmaf(a.y, b.y, fmaf(a.z, b.z, a.w * b.w)));
}

__device__ __forceinline__ float red16(float s) {
    s += __shfl_xor(s, 1);
    s += __shfl_xor(s, 2);
    s += __shfl_xor(s, 4);
    s += __shfl_xor(s, 8);
    return s;
}

__global__ __launch_bounds__(256) void gnn_edge_head_kernel(
    const float* __restrict__ nf,     // [N, 64]
    const int*   __restrict__ src,    // [E]
    const int*   __restrict__ dst,    // [E]
    const int*   __restrict__ neg,    // [E, 8]
    const int*   __restrict__ label,  // [E]
    float*       __restrict__ out,    // [E*9 + E]
    int E)
{
    const int sub = threadIdx.x & 15;
    const int grp = threadIdx.x >> 4;
    const int gpb = blockDim.x >> 4;
    const int stride = gridDim.x * gpb;
    const float4* __restrict__ nf4 = reinterpret_cast<const float4*>(nf);
    const int4*   __restrict__ neg4 = reinterpret_cast<const int4*>(neg);

    for (int e = blockIdx.x * gpb + grp; e < E; e += stride) {
        // --- index loads (coalesced / dedup'd by the wave coalescer) ---
        const int  us  = src[e];
        const int  vs  = dst[e];
        const int4 nA  = neg4[e * 2 + 0];
        const int4 nB  = neg4[e * 2 + 1];
        const int  lab = label[e];

        // --- all 10 row gathers in flight before any use ---
        const float4 u4 = nf4[(size_t)us   * 16 + sub];
        const float4 v4 = nf4[(size_t)vs   * 16 + sub];
        const float4 g0 = nf4[(size_t)nA.x * 16 + sub];
        const float4 g1 = nf4[(size_t)nA.y * 16 + sub];
        const float4 g2 = nf4[(size_t)nA.z * 16 + sub];
        const float4 g3 = nf4[(size_t)nA.w * 16 + sub];
        const float4 g4 = nf4[(size_t)nB.x * 16 + sub];
        const float4 g5 = nf4[(size_t)nB.y * 16 + sub];
        const float4 g6 = nf4[(size_t)nB.z * 16 + sub];
        const float4 g7 = nf4[(size_t)nB.w * 16 + sub];

        // --- partial dots (per-lane, 4 elements each) ---
        float p0 = dot4(u4, v4);
        float p1 = dot4(u4, g0);
        float p2 = dot4(u4, g1);
        float p3 = dot4(u4, g2);
        float p4 = dot4(u4, g3);
        float p5 = dot4(u4, g4);
        float p6 = dot4(u4, g5);
        float p7 = dot4(u4, g6);
        float p8 = dot4(u4, g7);

        // --- butterflies (all lanes end with full sums) ---
        p0 = red16(p0); p1 = red16(p1); p2 = red16(p2);
        p3 = red16(p3); p4 = red16(p4); p5 = red16(p5);
        p6 = red16(p6); p7 = red16(p7); p8 = red16(p8);

        // --- select-chain: lane sub (<9) holds p[sub]; one coalesced store ---
        float val = p0;
        val = (sub == 1) ? p1 : val;
        val = (sub == 2) ? p2 : val;
        val = (sub == 3) ? p3 : val;
        val = (sub == 4) ? p4 : val;
        val = (sub == 5) ? p5 : val;
        val = (sub == 6) ? p6 : val;
        val = (sub == 7) ? p7 : val;
        val = (sub == 8) ? p8 : val;
        if (sub < 9) out[(size_t)e * 9 + sub] = val;

        // second output: edge_label cast to float
        if (sub == 9) out[(size_t)E * 9 + e] = (float)lab;
    }
}

extern "C" void kernel_launch(void* const* d_in, const int* in_sizes, int n_in,
                              void* d_out, int out_size, void* d_ws, size_t ws_size,
                              hipStream_t stream)
{
    const float* nf    = (const float*)d_in[0];   // [N*64] f32
    const int*   eli   = (const int*)d_in[1];     // [2*E]
    const int*   neg   = (const int*)d_in[2];     // [E*8]
    const int*   label = (const int*)d_in[3];     // [E]
    float*       out   = (float*)d_out;

    const int E = in_sizes[3];                    // 262144
    const int* src = eli;
    const int* dst = eli + E;

    const int block = 256;
    const int groupsPerBlock = block / 16;        // 16 edges per block
    const int grid = (E + groupsPerBlock - 1) / groupsPerBlock;  // 16384

    gnn_edge_head_kernel<<<grid, block, 0, stream>>>(nf, src, dst, neg, label, out, E);
}